// Round 1
// baseline (106.959 us; speedup 1.0000x reference)
//
#include <hip/hip_runtime.h>
#include <hip/hip_bf16.h>

// Problem constants (SelectSphereConv, graph level 6)
#define VN 40962
#define BN 4
#define CN 64
#define KN 9
#define ON 64
#define KK 576            // CN*KN, GEMM reduction dim
#define NKS 18            // KK/32 K-steps for 16x16x32 MFMA
#define NV 8              // vertices per block-group
#define NGROUPS 5121      // ceil(VN/NV)
#define GRID_FUSED 768    // 3 blocks/CU * 256 CU
#define LDA_B 1168        // A_lds row stride in bytes: 576*2 + 16 pad (16B-aligned, conflict-free b128)

typedef float f32x4 __attribute__((ext_vector_type(4)));
typedef float f32x2 __attribute__((ext_vector_type(2)));
typedef __bf16 bf16x8 __attribute__((ext_vector_type(8)));

// ---------------------------------------------------------------------------
// Kernel 1: transpose x [256(t=b*64+c), V] f32 -> x_t [V, 256] bf16
// ---------------------------------------------------------------------------
__global__ __launch_bounds__(256) void k_transpose(const float* __restrict__ x,
                                                   __bf16* __restrict__ xt) {
    __shared__ __bf16 tile[64][65];   // pad 65: 2-way (free) bank aliasing on transposed read
    const int v0 = blockIdx.x * 64;
    const int t0 = blockIdx.y * 64;
    const int lane = threadIdx.x & 63;
    const int sub = threadIdx.x >> 6;  // 0..3

#pragma unroll
    for (int r = 0; r < 16; ++r) {
        const int t = t0 + r * 4 + sub;       // always < 256
        const int v = v0 + lane;
        float val = (v < VN) ? x[(size_t)t * VN + v] : 0.f;  // coalesced 256B/wave
        tile[r * 4 + sub][lane] = (__bf16)val;
    }
    __syncthreads();
#pragma unroll
    for (int r = 0; r < 16; ++r) {
        const int vv = r * 4 + sub;
        const int v = v0 + vv;
        if (v < VN) xt[(size_t)v * 256 + t0 + lane] = tile[lane][vv];  // coalesced 128B/wave
    }
}

// ---------------------------------------------------------------------------
// Kernel 2: fused gather + interpolate (VALU) + conv (MFMA)
//   A-tile rows: r = vv*4 + b  (32 rows = 8 vertices x 4 batch)
//   K index:     c*9 + j       (matches conv_w row layout [o][c][j])
//   N cols:      o (64), one 16-col tile per wave, W fragments in registers
// ---------------------------------------------------------------------------
__global__ __launch_bounds__(256, 3) void k_fused(const __bf16* __restrict__ xt,
                                                  const int* __restrict__ index,
                                                  const float* __restrict__ itp_mat,
                                                  const float* __restrict__ conv_w,
                                                  const float* __restrict__ conv_b,
                                                  float* __restrict__ out) {
    __shared__ char smem[32 * LDA_B];  // 37376 B: A-tile, reused as C staging

    const int tid  = threadIdx.x;
    const int lane = tid & 63;
    const int wave = tid >> 6;      // also the batch index b in phase 1 / epilogue
    const int l16  = lane & 15;
    const int g4   = lane >> 4;     // 0..3
    const int kb   = g4 * 8;        // k-base within a 32-wide K-step

    // ---- load W fragments into registers: 18 ksteps x 8 bf16 = 72 VGPR ----
    bf16x8 wfrag[NKS];
    {
        const int o = wave * 16 + l16;                 // this wave's output-col for lane
        const float* wrow = conv_w + (size_t)o * KK;   // 576 contiguous f32
#pragma unroll
        for (int ks = 0; ks < NKS; ++ks) {
            f32x4 w0 = *(const f32x4*)(wrow + ks * 32 + kb);
            f32x4 w1 = *(const f32x4*)(wrow + ks * 32 + kb + 4);
            bf16x8 f;
            f[0] = (__bf16)w0[0]; f[1] = (__bf16)w0[1];
            f[2] = (__bf16)w0[2]; f[3] = (__bf16)w0[3];
            f[4] = (__bf16)w1[0]; f[5] = (__bf16)w1[1];
            f[6] = (__bf16)w1[2]; f[7] = (__bf16)w1[3];
            wfrag[ks] = f;
        }
    }

    const int b_of = wave;          // tid>>6
    const int c_of = tid & 63;
    const float bias_v = conv_b[c_of];   // epilogue: o = tid&63

    for (int g = blockIdx.x; g < NGROUPS; g += gridDim.x) {
        const int v0 = g * NV;
        __syncthreads();  // A_lds free (prev epilogue done)

        // ---------------- phase 1: gather + interpolate ----------------
#pragma unroll
        for (int vv = 0; vv < NV; ++vv) {
            const int v = v0 + vv;
            if (v >= VN) break;                         // uniform
            const int* idxv = index + (size_t)v * KN;   // wave-uniform -> s_load
            const float* am = itp_mat + (size_t)v * (KN * KN);  // uniform -> s_load
            float gv[KN];
#pragma unroll
            for (int k = 0; k < KN; ++k) {
                const int nb = idxv[k];
                gv[k] = (float)xt[(size_t)nb * 256 + tid];  // coalesced 128B/wave
            }
            float s[KN];
#pragma unroll
            for (int j = 0; j < KN; ++j) s[j] = 0.f;
#pragma unroll
            for (int k = 0; k < KN; ++k) {
                const float gk = gv[k];
#pragma unroll
                for (int j = 0; j < KN; ++j) s[j] += gk * am[k * KN + j];
            }
            __bf16* rowp = (__bf16*)(smem + (vv * 4 + b_of) * LDA_B) + c_of * KN;
#pragma unroll
            for (int j = 0; j < KN; ++j) rowp[j] = (__bf16)s[j];
        }
        __syncthreads();

        // ---------------- phase 2: MFMA conv ----------------
        f32x4 acc0 = {0.f, 0.f, 0.f, 0.f};
        f32x4 acc1 = {0.f, 0.f, 0.f, 0.f};
        {
            const char* arow0 = smem + l16 * LDA_B + kb * 2;        // rows 0..15
            const char* arow1 = arow0 + 16 * LDA_B;                 // rows 16..31
#pragma unroll
            for (int ks = 0; ks < NKS; ++ks) {
                bf16x8 a0 = *(const bf16x8*)(arow0 + ks * 64);
                bf16x8 a1 = *(const bf16x8*)(arow1 + ks * 64);
                acc0 = __builtin_amdgcn_mfma_f32_16x16x32_bf16(a0, wfrag[ks], acc0, 0, 0, 0);
                acc1 = __builtin_amdgcn_mfma_f32_16x16x32_bf16(a1, wfrag[ks], acc1, 0, 0, 0);
            }
        }
        __syncthreads();  // done reading A_lds

        // ---------------- C staging through LDS ----------------
        float* c_lds = (float*)smem;   // [32 rows][65] f32 = 8320 B
        {
            const int ocol = wave * 16 + l16;
#pragma unroll
            for (int r = 0; r < 4; ++r) {
                c_lds[(g4 * 4 + r) * 65 + ocol]        = acc0[r];
                c_lds[(16 + g4 * 4 + r) * 65 + ocol]   = acc1[r];
            }
        }
        __syncthreads();

        // ---------------- epilogue: coalesced-ish 8-float rows ----------------
        {
            float vals[NV];
#pragma unroll
            for (int vv = 0; vv < NV; ++vv)
                vals[vv] = c_lds[(vv * 4 + b_of) * 65 + c_of] + bias_v;
            float* op = out + (size_t)tid * VN + v0;   // out[(b*64+o)*V + v], tid == b*64+o
            const int vleft = VN - v0;
            if (vleft >= NV) {
                // rows are only 8B-aligned (V%4==2) -> float2 stores
                *(f32x2*)(op + 0) = {vals[0], vals[1]};
                *(f32x2*)(op + 2) = {vals[2], vals[3]};
                *(f32x2*)(op + 4) = {vals[4], vals[5]};
                *(f32x2*)(op + 6) = {vals[6], vals[7]};
            } else {
                for (int vv = 0; vv < vleft; ++vv) op[vv] = vals[vv];
            }
        }
    }
}

// ---------------------------------------------------------------------------
extern "C" void kernel_launch(void* const* d_in, const int* in_sizes, int n_in,
                              void* d_out, int out_size, void* d_ws, size_t ws_size,
                              hipStream_t stream) {
    const float* x       = (const float*)d_in[0];
    const int*   index   = (const int*)d_in[1];
    const float* itp_mat = (const float*)d_in[2];
    const float* conv_w  = (const float*)d_in[3];
    const float* conv_b  = (const float*)d_in[4];
    float* out = (float*)d_out;

    __bf16* xt = (__bf16*)d_ws;   // needs VN*256*2 = 20,972,544 B of workspace

    dim3 tgrid((VN + 63) / 64, 4, 1);
    k_transpose<<<tgrid, 256, 0, stream>>>(x, xt);
    k_fused<<<GRID_FUSED, 256, 0, stream>>>(xt, index, itp_mat, conv_w, conv_b, out);
}